// Round 2
// baseline (826.551 us; speedup 1.0000x reference)
//
#include <hip/hip_runtime.h>
#include <stdint.h>

// Binarized MLP forward, MI355X.
// Pipeline:
//  prep_x: x fp32 -> interleaved (hi,lo) bf16 pairs, K padded 1568->1600
//  prep_w: W -> sign(W) duplicated along K (bf16)
//  gemm1 (MFMA bf16 16x16x32, 128x128 tile, global_load_lds, XCD-swizzled): z1 fp32
//  col_stats + bn_finalize -> scale/shift
//  bn_relu_split: h1 = relu(BN(z1)) -> hi/lo bf16 pairs
//  gemm2 (+relu epilogue): r2 = relu(h1n @ sW2^T) fp32
//  col_stats + bn_finalize
//  gemm3_softmax: fp32 vector GEMM (C=10) + BN-on-the-fly + relu + softmax

using u16 = unsigned short;
typedef u16 u16x8 __attribute__((ext_vector_type(8)));
typedef __bf16 bf16x8 __attribute__((ext_vector_type(8)));
typedef float f32x4 __attribute__((ext_vector_type(4)));

#define NB 32768
#define KP1 1600
#define K2 2048

__device__ __forceinline__ u16 f2bf(float f) {
  uint32_t u = __float_as_uint(f);
  u += 0x7FFF + ((u >> 16) & 1);   // round-to-nearest-even
  return (u16)(u >> 16);
}
__device__ __forceinline__ float bf2f(u16 h) {
  return __uint_as_float(((uint32_t)h) << 16);
}

__device__ __forceinline__ void gload_lds16(const void* g, void* l) {
  __builtin_amdgcn_global_load_lds(
      (const __attribute__((address_space(1))) uint32_t*)g,
      (__attribute__((address_space(3))) uint32_t*)l, 16, 0, 0);
}

// x [NB,784] fp32 -> xhl [NB,1600] bf16 (hi,lo interleaved, cols 1568.. zero)
__global__ void prep_x_kernel(const float* __restrict__ x, u16* __restrict__ xhl) {
  int gid = blockIdx.x * 256 + threadIdx.x;   // NB*200 threads
  int row = gid / 200, slot = gid % 200;
  u16x8 o = {0, 0, 0, 0, 0, 0, 0, 0};
  if (slot < 196) {
    float4 v = *reinterpret_cast<const float4*>(x + (size_t)row * 784 + slot * 4);
    float vv[4] = {v.x, v.y, v.z, v.w};
#pragma unroll
    for (int e = 0; e < 4; ++e) {
      u16 hi = f2bf(vv[e]);
      u16 lo = f2bf(vv[e] - bf2f(hi));
      o[2 * e] = hi;
      o[2 * e + 1] = lo;
    }
  }
  *reinterpret_cast<u16x8*>(xhl + (size_t)row * KP1 + slot * 8) = o;
}

// W [rows, in_slots*4] fp32 -> sign duplicated [rows, out_slots*8] bf16
__global__ void prep_wdup_kernel(const float* __restrict__ w, u16* __restrict__ o,
                                 int in_slots, int out_slots) {
  int gid = blockIdx.x * 256 + threadIdx.x;
  int row = gid / out_slots, slot = gid % out_slots;
  u16x8 r = {0, 0, 0, 0, 0, 0, 0, 0};
  if (slot < in_slots) {
    float4 v = *reinterpret_cast<const float4*>(w + (size_t)row * (in_slots * 4) + slot * 4);
    float vv[4] = {v.x, v.y, v.z, v.w};
#pragma unroll
    for (int e = 0; e < 4; ++e) {
      u16 s = vv[e] > 0.f ? (u16)0x3F80 : (vv[e] < 0.f ? (u16)0xBF80 : (u16)0);
      r[2 * e] = s;
      r[2 * e + 1] = s;
    }
  }
  *reinterpret_cast<u16x8*>(o + (size_t)row * (out_slots * 8) + slot * 8) = r;
}

// C[M,N] = A[M,K] * Bm[N,K]^T, bf16 in fp32 out. m97 structure:
// 128x128 tile, BK=64, 4 waves (2x2 of 64x64), single-buffer LDS, gload_lds16.
// XCD swizzle (m157): grid must be a multiple of 8.
template <int RELU>
__global__ void gemm_bt_kernel(const u16* __restrict__ A, const u16* __restrict__ Bm,
                               float* __restrict__ C, int M, int N, int K, int nbn) {
  __shared__ u16 As[128 * 64];
  __shared__ u16 Bs[128 * 64];
  const int tid = threadIdx.x;
  const int lane = tid & 63;
  const int w = tid >> 6;
  const int wr = w >> 1, wc = w & 1;
  // XCD-aware swizzle: HW assigns blockIdx.x round-robin to XCDs (bid%8).
  // Map so each XCD gets a CONTIGUOUS logical chunk -> A-panels + B stay in
  // that XCD's 4MB L2. Bijective because gridDim.x % 8 == 0.
  const int cpx = gridDim.x >> 3;
  const int bid = (blockIdx.x & 7) * cpx + (blockIdx.x >> 3);
  const int m0 = (bid / nbn) * 128;
  const int n0 = (bid % nbn) * 128;

  f32x4 acc[4][4];
  const f32x4 z4 = {0.f, 0.f, 0.f, 0.f};
#pragma unroll
  for (int i = 0; i < 4; ++i)
#pragma unroll
    for (int j = 0; j < 4; ++j) acc[i][j] = z4;

  // staging: 16 chunks of 1KB (8 rows x 128B); wave w owns chunks w*4..w*4+3
  const int lrow = lane >> 3;
  const int lcolb = (lane & 7) * 16;
  const char* aP[4];
  const char* bP[4];
  u16* aL[4];
  u16* bL[4];
#pragma unroll
  for (int i = 0; i < 4; ++i) {
    int c = w * 4 + i;
    int row = c * 8 + lrow;
    aP[i] = (const char*)(A + (size_t)(m0 + row) * K) + lcolb;
    bP[i] = (const char*)(Bm + (size_t)(n0 + row) * K) + lcolb;
    aL[i] = &As[c * 512];
    bL[i] = &Bs[c * 512];
  }

  const int lr = lane & 15;
  const int ko = (lane >> 4) * 8;

  for (int k0 = 0; k0 < K; k0 += 64) {
#pragma unroll
    for (int i = 0; i < 4; ++i) {
      gload_lds16(aP[i] + (size_t)k0 * 2, aL[i]);
      gload_lds16(bP[i] + (size_t)k0 * 2, bL[i]);
    }
    __syncthreads();  // compiler emits vmcnt(0) drain before barrier
#pragma unroll
    for (int kk = 0; kk < 64; kk += 32) {
      bf16x8 af[4], bf[4];
#pragma unroll
      for (int mi = 0; mi < 4; ++mi)
        af[mi] = *reinterpret_cast<const bf16x8*>(&As[(wr * 64 + mi * 16 + lr) * 64 + kk + ko]);
#pragma unroll
      for (int ni = 0; ni < 4; ++ni)
        bf[ni] = *reinterpret_cast<const bf16x8*>(&Bs[(wc * 64 + ni * 16 + lr) * 64 + kk + ko]);
#pragma unroll
      for (int mi = 0; mi < 4; ++mi)
#pragma unroll
        for (int ni = 0; ni < 4; ++ni)
          acc[mi][ni] =
              __builtin_amdgcn_mfma_f32_16x16x32_bf16(af[mi], bf[ni], acc[mi][ni], 0, 0, 0);
    }
    __syncthreads();
  }

  // C/D layout (m89-verified): col = lane&15, row = (lane>>4)*4 + i
  const int rq = lane >> 4;
#pragma unroll
  for (int mi = 0; mi < 4; ++mi)
#pragma unroll
    for (int ni = 0; ni < 4; ++ni)
#pragma unroll
      for (int i = 0; i < 4; ++i) {
        int r = m0 + wr * 64 + mi * 16 + rq * 4 + i;
        int cc = n0 + wc * 64 + ni * 16 + lr;
        float v = acc[mi][ni][i];
        if (RELU) v = fmaxf(v, 0.f);
        C[(size_t)r * N + cc] = v;
      }
}

// per-column sum & sumsq of z [NB, N] -> sums[0..N-1]=sum, sums[N..2N-1]=sumsq
__global__ void col_stats_kernel(const float* __restrict__ z, float* __restrict__ sums,
                                 int N, int rows_per) {
  int c = blockIdx.x * 256 + threadIdx.x;
  size_t r0 = (size_t)blockIdx.y * rows_per;
  float s = 0.f, s2 = 0.f;
  for (int r = 0; r < rows_per; ++r) {
    float v = z[(r0 + r) * N + c];
    s += v;
    s2 += v * v;
  }
  atomicAdd(&sums[c], s);
  atomicAdd(&sums[N + c], s2);
}

// coef[c] = g*rsqrt(var+eps); coef[N+c] = b - mu*scale
__global__ void bn_finalize_kernel(const float* __restrict__ sums, const float* __restrict__ g,
                                   const float* __restrict__ b, float* __restrict__ coef,
                                   int N, float invB) {
  int c = blockIdx.x * 256 + threadIdx.x;
  float mu = sums[c] * invB;
  float var = fmaxf(sums[N + c] * invB - mu * mu, 0.f);
  float sc = g[c] * rsqrtf(var + 1e-5f);
  coef[c] = sc;
  coef[N + c] = b[c] - mu * sc;
}

// h = relu(scale*z + shift); write hi/lo bf16 pairs [NB, 2048]
__global__ void bn_relu_split_kernel(const float* __restrict__ z, const float* __restrict__ coef,
                                     u16* __restrict__ out) {
  int gid = blockIdx.x * 256 + threadIdx.x;  // NB*256 threads, 4 elems each
  int row = gid >> 8;
  int slot = gid & 255;
  float4 v = *reinterpret_cast<const float4*>(z + (size_t)row * 1024 + slot * 4);
  float4 sc = *reinterpret_cast<const float4*>(coef + slot * 4);
  float4 sh = *reinterpret_cast<const float4*>(coef + 1024 + slot * 4);
  float hv[4] = {fmaxf(v.x * sc.x + sh.x, 0.f), fmaxf(v.y * sc.y + sh.y, 0.f),
                 fmaxf(v.z * sc.z + sh.z, 0.f), fmaxf(v.w * sc.w + sh.w, 0.f)};
  u16x8 o;
#pragma unroll
  for (int e = 0; e < 4; ++e) {
    u16 hi = f2bf(hv[e]);
    u16 lo = f2bf(hv[e] - bf2f(hi));
    o[2 * e] = hi;
    o[2 * e + 1] = lo;
  }
  *reinterpret_cast<u16x8*>(out + (size_t)row * 2048 + slot * 8) = o;
}

// layer 3: BN2 applied on the fly (no relu before BN here -- BN(relu(.)) already
// baked into r2+coef), z3 = h2n @ sign(W3)^T, relu, softmax. One wave per row.
__global__ void gemm3_softmax_kernel(const float* __restrict__ r2, const float* __restrict__ coef,
                                     const float* __restrict__ W3, float* __restrict__ out) {
  __shared__ float s3[10 * 1024];
  __shared__ float cf[2048];
  const int tid = threadIdx.x;
  for (int i = tid; i < 10 * 1024; i += 256) {
    float wv = W3[i];
    s3[i] = wv > 0.f ? 1.f : (wv < 0.f ? -1.f : 0.f);
  }
  for (int i = tid; i < 2048; i += 256) cf[i] = coef[i];
  __syncthreads();
  const int lane = tid & 63;
  const int wid = tid >> 6;
  const size_t row = (size_t)blockIdx.x * 4 + wid;
  float h[16];
#pragma unroll
  for (int j = 0; j < 4; ++j) {
    float4 v = *reinterpret_cast<const float4*>(r2 + row * 1024 + j * 256 + lane * 4);
    float4 sc = *reinterpret_cast<const float4*>(&cf[j * 256 + lane * 4]);
    float4 sh = *reinterpret_cast<const float4*>(&cf[1024 + j * 256 + lane * 4]);
    h[j * 4 + 0] = v.x * sc.x + sh.x;
    h[j * 4 + 1] = v.y * sc.y + sh.y;
    h[j * 4 + 2] = v.z * sc.z + sh.z;
    h[j * 4 + 3] = v.w * sc.w + sh.w;
  }
  float l[10];
#pragma unroll
  for (int c = 0; c < 10; ++c) {
    float a = 0.f;
#pragma unroll
    for (int j = 0; j < 4; ++j) {
      float4 s = *reinterpret_cast<const float4*>(&s3[c * 1024 + j * 256 + lane * 4]);
      a += h[j * 4 + 0] * s.x + h[j * 4 + 1] * s.y + h[j * 4 + 2] * s.z + h[j * 4 + 3] * s.w;
    }
#pragma unroll
    for (int m = 1; m < 64; m <<= 1) a += __shfl_xor(a, m, 64);
    l[c] = fmaxf(a, 0.f);
  }
  float mx = l[0];
#pragma unroll
  for (int c = 1; c < 10; ++c) mx = fmaxf(mx, l[c]);
  float se = 0.f;
#pragma unroll
  for (int c = 0; c < 10; ++c) {
    l[c] = expf(l[c] - mx);
    se += l[c];
  }
  float inv = 1.f / se;
  float pv = 0.f;
#pragma unroll
  for (int c = 0; c < 10; ++c)
    if (lane == c) pv = l[c] * inv;
  if (lane < 10) out[row * 10 + lane] = pv;
}

extern "C" void kernel_launch(void* const* d_in, const int* in_sizes, int n_in,
                              void* d_out, int out_size, void* d_ws, size_t ws_size,
                              hipStream_t stream) {
  const float* x = (const float*)d_in[0];
  const float* W1 = (const float*)d_in[1];
  const float* g1 = (const float*)d_in[2];
  const float* b1 = (const float*)d_in[3];
  const float* W2 = (const float*)d_in[4];
  const float* g2 = (const float*)d_in[5];
  const float* b2 = (const float*)d_in[6];
  const float* W3 = (const float*)d_in[7];
  float* out = (float*)d_out;

  char* ws = (char*)d_ws;
  size_t off = 0;
  auto alloc = [&](size_t bytes) -> char* {
    char* p = ws + off;
    off += (bytes + 255) & ~(size_t)255;
    return p;
  };
  u16* R1 = (u16*)alloc((size_t)NB * 2048 * 2);   // xhl (stride 1600) then h1hl (stride 2048)
  float* R2 = (float*)alloc((size_t)NB * 1024 * 4);  // z1 then r2
  u16* sW1 = (u16*)alloc((size_t)1024 * KP1 * 2);
  u16* sW2 = (u16*)alloc((size_t)1024 * K2 * 2);
  float* st1 = (float*)alloc(2048 * 4);
  float* cf1 = (float*)alloc(2048 * 4);
  float* st2 = (float*)alloc(2048 * 4);
  float* cf2 = (float*)alloc(2048 * 4);

  hipMemsetAsync(st1, 0, 2048 * 4, stream);
  hipMemsetAsync(st2, 0, 2048 * 4, stream);

  prep_x_kernel<<<(NB * 200) / 256, 256, 0, stream>>>(x, R1);
  prep_wdup_kernel<<<(1024 * 200) / 256, 256, 0, stream>>>(W1, sW1, 196, 200);
  prep_wdup_kernel<<<(1024 * 256) / 256, 256, 0, stream>>>(W2, sW2, 256, 256);

  gemm_bt_kernel<0><<<(NB / 128) * (1024 / 128), 256, 0, stream>>>(R1, sW1, R2, NB, 1024, KP1, 8);
  col_stats_kernel<<<dim3(4, 64), 256, 0, stream>>>(R2, st1, 1024, NB / 64);
  bn_finalize_kernel<<<4, 256, 0, stream>>>(st1, g1, b1, cf1, 1024, 1.f / (float)NB);
  bn_relu_split_kernel<<<NB, 256, 0, stream>>>(R2, cf1, R1);

  gemm_bt_kernel<1><<<(NB / 128) * (1024 / 128), 256, 0, stream>>>(R1, sW2, R2, NB, 1024, K2, 8);
  col_stats_kernel<<<dim3(4, 64), 256, 0, stream>>>(R2, st2, 1024, NB / 64);
  bn_finalize_kernel<<<4, 256, 0, stream>>>(st2, g2, b2, cf2, 1024, 1.f / (float)NB);

  gemm3_softmax_kernel<<<NB / 4, 256, 0, stream>>>(R2, cf2, W3, out);
}

// Round 3
// 575.791 us; speedup vs baseline: 1.4355x; 1.4355x over previous
//
#include <hip/hip_runtime.h>
#include <stdint.h>

// Binarized MLP forward, MI355X.
// Pipeline (8 launches):
//  memset st (stats accumulators)
//  prep_x: x fp32 -> interleaved (hi,lo) bf16 pairs, K padded 1568->1600
//  prep_w x2: W -> sign(W) duplicated along K (bf16)
//  gemm1 (MFMA bf16, 128x128 tile, XCD-swizzled) + fused col sum/sumsq epilogue
//  bn_relu_split (+fused bn_finalize): h1 = relu(BN(z1)) -> hi/lo bf16 pairs
//  gemm2 (+relu epilogue) + fused col stats of relu'd output
//  gemm3_softmax (+fused bn_finalize): BN + z3 + relu + softmax

using u16 = unsigned short;
typedef u16 u16x8 __attribute__((ext_vector_type(8)));
typedef __bf16 bf16x8 __attribute__((ext_vector_type(8)));
typedef float f32x4 __attribute__((ext_vector_type(4)));

#define NB 32768
#define KP1 1600
#define K2 2048

__device__ __forceinline__ u16 f2bf(float f) {
  uint32_t u = __float_as_uint(f);
  u += 0x7FFF + ((u >> 16) & 1);   // round-to-nearest-even
  return (u16)(u >> 16);
}
__device__ __forceinline__ float bf2f(u16 h) {
  return __uint_as_float(((uint32_t)h) << 16);
}

__device__ __forceinline__ void gload_lds16(const void* g, void* l) {
  __builtin_amdgcn_global_load_lds(
      (const __attribute__((address_space(1))) uint32_t*)g,
      (__attribute__((address_space(3))) uint32_t*)l, 16, 0, 0);
}

// x [NB,784] fp32 -> xhl [NB,1600] bf16 (hi,lo interleaved, cols 1568.. zero)
__global__ void prep_x_kernel(const float* __restrict__ x, u16* __restrict__ xhl) {
  int gid = blockIdx.x * 256 + threadIdx.x;   // NB*200 threads
  int row = gid / 200, slot = gid % 200;
  u16x8 o = {0, 0, 0, 0, 0, 0, 0, 0};
  if (slot < 196) {
    float4 v = *reinterpret_cast<const float4*>(x + (size_t)row * 784 + slot * 4);
    float vv[4] = {v.x, v.y, v.z, v.w};
#pragma unroll
    for (int e = 0; e < 4; ++e) {
      u16 hi = f2bf(vv[e]);
      u16 lo = f2bf(vv[e] - bf2f(hi));
      o[2 * e] = hi;
      o[2 * e + 1] = lo;
    }
  }
  *reinterpret_cast<u16x8*>(xhl + (size_t)row * KP1 + slot * 8) = o;
}

// W [rows, in_slots*4] fp32 -> sign duplicated [rows, out_slots*8] bf16
__global__ void prep_wdup_kernel(const float* __restrict__ w, u16* __restrict__ o,
                                 int in_slots, int out_slots) {
  int gid = blockIdx.x * 256 + threadIdx.x;
  int row = gid / out_slots, slot = gid % out_slots;
  u16x8 r = {0, 0, 0, 0, 0, 0, 0, 0};
  if (slot < in_slots) {
    float4 v = *reinterpret_cast<const float4*>(w + (size_t)row * (in_slots * 4) + slot * 4);
    float vv[4] = {v.x, v.y, v.z, v.w};
#pragma unroll
    for (int e = 0; e < 4; ++e) {
      u16 s = vv[e] > 0.f ? (u16)0x3F80 : (vv[e] < 0.f ? (u16)0xBF80 : (u16)0);
      r[2 * e] = s;
      r[2 * e + 1] = s;
    }
  }
  *reinterpret_cast<u16x8*>(o + (size_t)row * (out_slots * 8) + slot * 8) = r;
}

// C[M,N] = A[M,K] * Bm[N,K]^T, bf16 in fp32 out. m97 structure:
// 128x128 tile, BK=64, 4 waves (2x2 of 64x64), single-buffer LDS, gload_lds16,
// XCD swizzle (grid must be a multiple of 8).
// Fused epilogue: per-column sum & sumsq of the written value (post-relu if
// RELU) atomically accumulated into st[0..N-1]=sum, st[N..2N-1]=sumsq.
template <int RELU>
__global__ void gemm_bt_kernel(const u16* __restrict__ A, const u16* __restrict__ Bm,
                               float* __restrict__ C, float* __restrict__ st,
                               int M, int N, int K, int nbn) {
  __shared__ u16 As[128 * 64];
  __shared__ u16 Bs[128 * 64];
  const int tid = threadIdx.x;
  const int lane = tid & 63;
  const int w = tid >> 6;
  const int wr = w >> 1, wc = w & 1;
  // XCD-aware swizzle: HW assigns blockIdx.x round-robin to XCDs (bid%8).
  const int cpx = gridDim.x >> 3;
  const int bid = (blockIdx.x & 7) * cpx + (blockIdx.x >> 3);
  const int m0 = (bid / nbn) * 128;
  const int n0 = (bid % nbn) * 128;

  f32x4 acc[4][4];
  const f32x4 z4 = {0.f, 0.f, 0.f, 0.f};
#pragma unroll
  for (int i = 0; i < 4; ++i)
#pragma unroll
    for (int j = 0; j < 4; ++j) acc[i][j] = z4;

  // staging: 16 chunks of 1KB (8 rows x 128B); wave w owns chunks w*4..w*4+3
  const int lrow = lane >> 3;
  const int lcolb = (lane & 7) * 16;
  const char* aP[4];
  const char* bP[4];
  u16* aL[4];
  u16* bL[4];
#pragma unroll
  for (int i = 0; i < 4; ++i) {
    int c = w * 4 + i;
    int row = c * 8 + lrow;
    aP[i] = (const char*)(A + (size_t)(m0 + row) * K) + lcolb;
    bP[i] = (const char*)(Bm + (size_t)(n0 + row) * K) + lcolb;
    aL[i] = &As[c * 512];
    bL[i] = &Bs[c * 512];
  }

  const int lr = lane & 15;
  const int ko = (lane >> 4) * 8;

  for (int k0 = 0; k0 < K; k0 += 64) {
#pragma unroll
    for (int i = 0; i < 4; ++i) {
      gload_lds16(aP[i] + (size_t)k0 * 2, aL[i]);
      gload_lds16(bP[i] + (size_t)k0 * 2, bL[i]);
    }
    __syncthreads();  // compiler emits vmcnt(0) drain before barrier
#pragma unroll
    for (int kk = 0; kk < 64; kk += 32) {
      bf16x8 af[4], bf[4];
#pragma unroll
      for (int mi = 0; mi < 4; ++mi)
        af[mi] = *reinterpret_cast<const bf16x8*>(&As[(wr * 64 + mi * 16 + lr) * 64 + kk + ko]);
#pragma unroll
      for (int ni = 0; ni < 4; ++ni)
        bf[ni] = *reinterpret_cast<const bf16x8*>(&Bs[(wc * 64 + ni * 16 + lr) * 64 + kk + ko]);
#pragma unroll
      for (int mi = 0; mi < 4; ++mi)
#pragma unroll
        for (int ni = 0; ni < 4; ++ni)
          acc[mi][ni] =
              __builtin_amdgcn_mfma_f32_16x16x32_bf16(af[mi], bf[ni], acc[mi][ni], 0, 0, 0);
    }
    __syncthreads();
  }

  // C/D layout (m89-verified): col = lane&15, row = (lane>>4)*4 + i
  const int rq = lane >> 4;
  float cs[4] = {0.f, 0.f, 0.f, 0.f};   // per-ni column sum over this wave's 64 rows
  float cq[4] = {0.f, 0.f, 0.f, 0.f};   // per-ni column sumsq
#pragma unroll
  for (int mi = 0; mi < 4; ++mi)
#pragma unroll
    for (int ni = 0; ni < 4; ++ni)
#pragma unroll
      for (int i = 0; i < 4; ++i) {
        int r = m0 + wr * 64 + mi * 16 + rq * 4 + i;
        int cc = n0 + wc * 64 + ni * 16 + lr;
        float v = acc[mi][ni][i];
        if (RELU) v = fmaxf(v, 0.f);
        C[(size_t)r * N + cc] = v;
        cs[ni] += v;
        cq[ni] += v * v;
      }
  // reduce across the 4 row-groups (lanes differ in bits 4-5), then one
  // atomic per column from lanes 0..15.
#pragma unroll
  for (int ni = 0; ni < 4; ++ni) {
    float ss = cs[ni], qq = cq[ni];
    ss += __shfl_xor(ss, 16, 64);
    qq += __shfl_xor(qq, 16, 64);
    ss += __shfl_xor(ss, 32, 64);
    qq += __shfl_xor(qq, 32, 64);
    if (lane < 16) {
      int c = n0 + wc * 64 + ni * 16 + lane;
      atomicAdd(&st[c], ss);
      atomicAdd(&st[N + c], qq);
    }
  }
}

// h = relu(scale*z + shift) with coef computed in-kernel from raw sums;
// write hi/lo bf16 pairs [NB, 2048]. Block = 8 rows x 1024 cols.
__global__ void bn_relu_split_kernel(const float* __restrict__ z, const float* __restrict__ st,
                                     const float* __restrict__ g, const float* __restrict__ b,
                                     u16* __restrict__ out) {
  const int tid = threadIdx.x;
  const int r0 = blockIdx.x * 8;
  const int c0 = tid * 4;
  const float invB = 1.f / (float)NB;
  float4 sv = *reinterpret_cast<const float4*>(st + c0);
  float4 qv = *reinterpret_cast<const float4*>(st + 1024 + c0);
  float4 gv = *reinterpret_cast<const float4*>(g + c0);
  float4 bv = *reinterpret_cast<const float4*>(b + c0);
  float sc[4], sh[4];
  {
    float s[4] = {sv.x, sv.y, sv.z, sv.w};
    float q[4] = {qv.x, qv.y, qv.z, qv.w};
    float gg[4] = {gv.x, gv.y, gv.z, gv.w};
    float bb[4] = {bv.x, bv.y, bv.z, bv.w};
#pragma unroll
    for (int e = 0; e < 4; ++e) {
      float mu = s[e] * invB;
      float var = fmaxf(q[e] * invB - mu * mu, 0.f);
      sc[e] = gg[e] * rsqrtf(var + 1e-5f);
      sh[e] = bb[e] - mu * sc[e];
    }
  }
#pragma unroll
  for (int r = 0; r < 8; ++r) {
    float4 v = *reinterpret_cast<const float4*>(z + (size_t)(r0 + r) * 1024 + c0);
    float hv[4] = {fmaxf(v.x * sc[0] + sh[0], 0.f), fmaxf(v.y * sc[1] + sh[1], 0.f),
                   fmaxf(v.z * sc[2] + sh[2], 0.f), fmaxf(v.w * sc[3] + sh[3], 0.f)};
    u16x8 o;
#pragma unroll
    for (int e = 0; e < 4; ++e) {
      u16 hi = f2bf(hv[e]);
      u16 lo = f2bf(hv[e] - bf2f(hi));
      o[2 * e] = hi;
      o[2 * e + 1] = lo;
    }
    *reinterpret_cast<u16x8*>(out + (size_t)(r0 + r) * 2048 + tid * 8) = o;
  }
}

// layer 3: BN2 coef computed in-kernel from raw sums, z3 = h2n @ sign(W3)^T,
// relu, softmax. One wave per row, 4 rows per block.
__global__ void gemm3_softmax_kernel(const float* __restrict__ r2, const float* __restrict__ st,
                                     const float* __restrict__ g, const float* __restrict__ b,
                                     const float* __restrict__ W3, float* __restrict__ out) {
  __shared__ float s3[10 * 1024];
  __shared__ float cf[2048];
  const int tid = threadIdx.x;
  for (int i = tid; i < 10 * 1024; i += 256) {
    float wv = W3[i];
    s3[i] = wv > 0.f ? 1.f : (wv < 0.f ? -1.f : 0.f);
  }
  const float invB = 1.f / (float)NB;
  for (int i = tid; i < 1024; i += 256) {
    float mu = st[i] * invB;
    float var = fmaxf(st[1024 + i] * invB - mu * mu, 0.f);
    float sc = g[i] * rsqrtf(var + 1e-5f);
    cf[i] = sc;
    cf[1024 + i] = b[i] - mu * sc;
  }
  __syncthreads();
  const int lane = tid & 63;
  const int wid = tid >> 6;
  const size_t row = (size_t)blockIdx.x * 4 + wid;
  float h[16];
#pragma unroll
  for (int j = 0; j < 4; ++j) {
    float4 v = *reinterpret_cast<const float4*>(r2 + row * 1024 + j * 256 + lane * 4);
    float4 sc = *reinterpret_cast<const float4*>(&cf[j * 256 + lane * 4]);
    float4 sh = *reinterpret_cast<const float4*>(&cf[1024 + j * 256 + lane * 4]);
    h[j * 4 + 0] = v.x * sc.x + sh.x;
    h[j * 4 + 1] = v.y * sc.y + sh.y;
    h[j * 4 + 2] = v.z * sc.z + sh.z;
    h[j * 4 + 3] = v.w * sc.w + sh.w;
  }
  float l[10];
#pragma unroll
  for (int c = 0; c < 10; ++c) {
    float a = 0.f;
#pragma unroll
    for (int j = 0; j < 4; ++j) {
      float4 s = *reinterpret_cast<const float4*>(&s3[c * 1024 + j * 256 + lane * 4]);
      a += h[j * 4 + 0] * s.x + h[j * 4 + 1] * s.y + h[j * 4 + 2] * s.z + h[j * 4 + 3] * s.w;
    }
#pragma unroll
    for (int m = 1; m < 64; m <<= 1) a += __shfl_xor(a, m, 64);
    l[c] = fmaxf(a, 0.f);
  }
  float mx = l[0];
#pragma unroll
  for (int c = 1; c < 10; ++c) mx = fmaxf(mx, l[c]);
  float se = 0.f;
#pragma unroll
  for (int c = 0; c < 10; ++c) {
    l[c] = expf(l[c] - mx);
    se += l[c];
  }
  float inv = 1.f / se;
  float pv = 0.f;
#pragma unroll
  for (int c = 0; c < 10; ++c)
    if (lane == c) pv = l[c] * inv;
  if (lane < 10) out[row * 10 + lane] = pv;
}

extern "C" void kernel_launch(void* const* d_in, const int* in_sizes, int n_in,
                              void* d_out, int out_size, void* d_ws, size_t ws_size,
                              hipStream_t stream) {
  const float* x = (const float*)d_in[0];
  const float* W1 = (const float*)d_in[1];
  const float* g1 = (const float*)d_in[2];
  const float* b1 = (const float*)d_in[3];
  const float* W2 = (const float*)d_in[4];
  const float* g2 = (const float*)d_in[5];
  const float* b2 = (const float*)d_in[6];
  const float* W3 = (const float*)d_in[7];
  float* out = (float*)d_out;

  char* ws = (char*)d_ws;
  size_t off = 0;
  auto alloc = [&](size_t bytes) -> char* {
    char* p = ws + off;
    off += (bytes + 255) & ~(size_t)255;
    return p;
  };
  u16* R1 = (u16*)alloc((size_t)NB * 2048 * 2);      // xhl (stride 1600) then h1hl (stride 2048)
  float* R2 = (float*)alloc((size_t)NB * 1024 * 4);  // z1 then r2
  u16* sW1 = (u16*)alloc((size_t)1024 * KP1 * 2);
  u16* sW2 = (u16*)alloc((size_t)1024 * K2 * 2);
  float* st1 = (float*)alloc(2048 * 4);              // st1, st2 adjacent -> one memset
  float* st2 = (float*)alloc(2048 * 4);

  hipMemsetAsync(st1, 0, 2 * 2048 * 4 + 256, stream);

  prep_x_kernel<<<(NB * 200) / 256, 256, 0, stream>>>(x, R1);
  prep_wdup_kernel<<<(1024 * 200) / 256, 256, 0, stream>>>(W1, sW1, 196, 200);
  prep_wdup_kernel<<<(1024 * 256) / 256, 256, 0, stream>>>(W2, sW2, 256, 256);

  gemm_bt_kernel<0><<<(NB / 128) * (1024 / 128), 256, 0, stream>>>(R1, sW1, R2, st1, NB, 1024,
                                                                   KP1, 8);
  bn_relu_split_kernel<<<NB / 8, 256, 0, stream>>>(R2, st1, g1, b1, R1);

  gemm_bt_kernel<1><<<(NB / 128) * (1024 / 128), 256, 0, stream>>>(R1, sW2, R2, st2, NB, 1024,
                                                                   K2, 8);
  gemm3_softmax_kernel<<<NB / 4, 256, 0, stream>>>(R2, st2, g2, b2, W3, out);
}